// Round 8
// baseline (276.406 us; speedup 1.0000x reference)
//
#include <hip/hip_runtime.h>

#define SEQ 131072
#define DIM 256
#define DTC 0.1f
#define EPSC 1e-8f

typedef __attribute__((ext_vector_type(8))) short bf16x8;
typedef __attribute__((ext_vector_type(4))) float f32x4;
typedef __attribute__((ext_vector_type(4))) int   i32x4;

// f32 -> bf16 round-to-nearest-even (no NaN handling needed: data is bounded)
static __device__ __forceinline__ unsigned short f2bf(float f){
  unsigned int u = __builtin_bit_cast(unsigned int, f);
  u += 0x7fffu + ((u >> 16) & 1u);
  return (unsigned short)(u >> 16);
}

// ---------------------------------------------------------------------------
// Single-launch power chain (replaces 4 dependent launches; no grid.sync):
// block r computes row r of P = M1^T via (T-1) sequential mat-vec passes
//   v <- v * M1,  v0 = row_r(M1),  M1 = I + cH computed INLINE from H.
// Row dependency is only through v (block-local, in LDS) -> zero inter-block
// sync. H (512 KB) is streamed per pass, L2/L3-resident across blocks/passes.
// Writes P (f32, for the no-frag fallback) and the bf16 B-fragments of
// R = P - I in apply's per-thread layout.
// ---------------------------------------------------------------------------
__global__ __launch_bounds__(1024)
void k_power(const float* __restrict__ hr, const float* __restrict__ hi,
             const float* __restrict__ hbar, const int* __restrict__ ts,
             float* __restrict__ Pr, float* __restrict__ Pi,
             unsigned short* __restrict__ fragbuf)
{
  __shared__ float vr_[256], vi_[256];
  __shared__ float pr_[4][256], pi_[4][256];
  const int tid = threadIdx.x, c = tid & 255, q = tid >> 8;
  const int r = blockIdx.x;
  const float s = DTC / hbar[0];
  const int T = ts[0];

  // v0 = row r of M1
  if (q == 0){
    const float diag = (r == c) ? 1.0f : 0.0f;
    vr_[c] = diag + s * hi[r*256 + c];
    vi_[c] =       -s * hr[r*256 + c];
  }
  __syncthreads();

  // (T-1) passes of v <- v * M1  (4-way k-split over q)
  for (int p = 0; p < T - 1; ++p){
    float ar = 0.f, ai = 0.f;
    const int k0 = q * 64;
    #pragma unroll 8
    for (int k = k0; k < k0 + 64; ++k){
      const int idx = k*256 + c;                 // coalesced across c
      const float diag = (k == c) ? 1.0f : 0.0f;
      const float br = diag + s * hi[idx];       // M1[k][c] inline from H
      const float bi =       -s * hr[idx];
      const float xr = vr_[k], xi = vi_[k];      // LDS broadcast
      ar = fmaf(xr, br, fmaf(-xi, bi, ar));
      ai = fmaf(xr, bi, fmaf( xi, br, ai));
    }
    pr_[q][c] = ar; pi_[q][c] = ai;
    __syncthreads();
    if (q == 0){
      vr_[c] = pr_[0][c]+pr_[1][c]+pr_[2][c]+pr_[3][c];
      vi_[c] = pi_[0][c]+pi_[1][c]+pi_[2][c]+pi_[3][c];
    }
    __syncthreads();
  }

  // emit P row r (f32) + bf16 fragments of R = P - I
  if (q == 0){
    float vr = vr_[c], vi = vi_[c];
    if (T == 0){ vr = (r == c) ? 1.0f : 0.0f; vi = 0.0f; }   // scan never ran
    Pr[r*256 + c] = vr;
    Pi[r*256 + c] = vi;
    if (fragbuf){
      const int C = r, K = c;
      const float rr = vr - ((r == c) ? 1.0f : 0.0f);
      const int ftid = (C>>5)*64 + ((K>>3)&3)*16 + (C&15);
      const int fid  = (((C>>4)&1)*8 + (K>>5))*2;
      fragbuf[((size_t)fid*512     + ftid)*8 + (K&7)] = f2bf(rr);
      fragbuf[((size_t)(fid+1)*512 + ftid)*8 + (K&7)] = f2bf(vi);
    }
  }
}

// ---------------------------------------------------------------------------
// Main apply v6: 32-row blocks (grid 4096), B streamed from L2 per kt-step.
// Identical to r7's apply5 except LDS pitch 272 -> 264: row stride 528 B
// (= 33*16, b128-aligned); rows r and r+4 no longer alias the same banks
// (4-way conflict -> 2-way = free).
//   out = normalize_rows( q + q @ R^T ),  R = M^T_power - I (f32 residual).
// ---------------------------------------------------------------------------
template<int STORE_COMPLEX>
__global__ __launch_bounds__(512, 4)
void apply6(const float* __restrict__ psi_re, const float* __restrict__ psi_im,
            const unsigned short* __restrict__ fragbuf,
            const int* __restrict__ tsteps, float* __restrict__ out)
{
  __shared__ alignas(16) unsigned short a_re[32][264];
  __shared__ alignas(16) unsigned short a_im[32][264];
  __shared__ float partials[32][8];

  const int tid  = threadIdx.x;
  const int wv   = tid >> 6;
  const int lane = tid & 63;
  const int lq   = lane >> 4;   // 16-lane group
  const int lr   = lane & 15;
  const int brow = blockIdx.x << 5;   // 32 rows per block
  const int cbase = wv << 5;          // wave's 32 columns
  const int T = tsteps[0];
  const bf16x8* fb = reinterpret_cast<const bf16x8*>(fragbuf);

  // ---- staging loads: row srow, 16 consecutive cols (fully coalesced) ----
  const int srow  = tid >> 4;
  const int scol0 = (tid & 15) << 4;
  const float4* pre4 = reinterpret_cast<const float4*>(&psi_re[(size_t)(brow + srow)*DIM + scol0]);
  const float4* pim4 = reinterpret_cast<const float4*>(&psi_im[(size_t)(brow + srow)*DIM + scol0]);
  const float4 sr0 = pre4[0], sr1 = pre4[1], sr2 = pre4[2], sr3 = pre4[3];
  const float4 si0 = pim4[0], si1 = pim4[1], si2 = pim4[2], si3 = pim4[3];

  // ---- residual loads (D-frag layout), issued early; L1/L2-hot ----
  float qre[2][2][4], qim[2][2][4];
  #pragma unroll
  for (int rt = 0; rt < 2; ++rt)
    #pragma unroll
    for (int ct = 0; ct < 2; ++ct)
      #pragma unroll
      for (int j = 0; j < 4; ++j){
        const size_t off = (size_t)(brow + rt*16 + lq*4 + j)*DIM + cbase + ct*16 + lr;
        qre[rt][ct][j] = psi_re[off];
        qim[rt][ct][j] = psi_im[off];
      }

  // ---- hoisted kt=0 B-frags (avoid cold L2 latency in first MFMA phase) ----
  const bf16x8 hb_r0 = fb[( 0)*512 + tid];
  const bf16x8 hb_i0 = fb[( 1)*512 + tid];
  const bf16x8 hb_r1 = fb[(16)*512 + tid];
  const bf16x8 hb_i1 = fb[(17)*512 + tid];

  // ---- convert + wide LDS writes (2x b128 per array) ----
  {
    bf16x8 p0, p1;
    p0[0]=(short)f2bf(sr0.x); p0[1]=(short)f2bf(sr0.y); p0[2]=(short)f2bf(sr0.z); p0[3]=(short)f2bf(sr0.w);
    p0[4]=(short)f2bf(sr1.x); p0[5]=(short)f2bf(sr1.y); p0[6]=(short)f2bf(sr1.z); p0[7]=(short)f2bf(sr1.w);
    p1[0]=(short)f2bf(sr2.x); p1[1]=(short)f2bf(sr2.y); p1[2]=(short)f2bf(sr2.z); p1[3]=(short)f2bf(sr2.w);
    p1[4]=(short)f2bf(sr3.x); p1[5]=(short)f2bf(sr3.y); p1[6]=(short)f2bf(sr3.z); p1[7]=(short)f2bf(sr3.w);
    *reinterpret_cast<bf16x8*>(&a_re[srow][scol0])     = p0;
    *reinterpret_cast<bf16x8*>(&a_re[srow][scol0 + 8]) = p1;
    bf16x8 q0, q1;
    q0[0]=(short)f2bf(si0.x); q0[1]=(short)f2bf(si0.y); q0[2]=(short)f2bf(si0.z); q0[3]=(short)f2bf(si0.w);
    q0[4]=(short)f2bf(si1.x); q0[5]=(short)f2bf(si1.y); q0[6]=(short)f2bf(si1.z); q0[7]=(short)f2bf(si1.w);
    q1[0]=(short)f2bf(si2.x); q1[1]=(short)f2bf(si2.y); q1[2]=(short)f2bf(si2.z); q1[3]=(short)f2bf(si2.w);
    q1[4]=(short)f2bf(si3.x); q1[5]=(short)f2bf(si3.y); q1[6]=(short)f2bf(si3.z); q1[7]=(short)f2bf(si3.w);
    *reinterpret_cast<bf16x8*>(&a_im[srow][scol0])     = q0;
    *reinterpret_cast<bf16x8*>(&a_im[srow][scol0 + 8]) = q1;
  }
  __syncthreads();

  // ---- kt-outer complex MFMA; B streamed from L2 (4 x 16B per kt) ----
  f32x4 ar[2][2], ai[2][2];
  #pragma unroll
  for (int rt = 0; rt < 2; ++rt)
    #pragma unroll
    for (int ct = 0; ct < 2; ++ct){
      ar[rt][ct] = (f32x4){0.f,0.f,0.f,0.f};
      ai[rt][ct] = (f32x4){0.f,0.f,0.f,0.f};
    }

  #pragma unroll
  for (int kt = 0; kt < 8; ++kt){
    bf16x8 br0, bi0, br1, bi1;
    if (kt == 0){ br0 = hb_r0; bi0 = hb_i0; br1 = hb_r1; bi1 = hb_i1; }
    else {
      br0 = fb[((0*8 + kt)*2 + 0)*512 + tid];
      bi0 = fb[((0*8 + kt)*2 + 1)*512 + tid];
      br1 = fb[((1*8 + kt)*2 + 0)*512 + tid];
      bi1 = fb[((1*8 + kt)*2 + 1)*512 + tid];
    }
    #pragma unroll
    for (int rt = 0; rt < 2; ++rt){
      const bf16x8 apr = *reinterpret_cast<const bf16x8*>(&a_re[rt*16 + lr][kt*32 + lq*8]);
      const bf16x8 api = *reinterpret_cast<const bf16x8*>(&a_im[rt*16 + lr][kt*32 + lq*8]);
      const i32x4 tneg = __builtin_bit_cast(i32x4, api) ^ (i32x4)(int)0x80008000;
      const bf16x8 apin = __builtin_bit_cast(bf16x8, tneg);   // -qi (sign flip)
      // g_re = qr@Rr - qi@Ri ; g_im = qr@Ri + qi@Rr
      ar[rt][0] = __builtin_amdgcn_mfma_f32_16x16x32_bf16(apr,  br0, ar[rt][0], 0,0,0);
      ar[rt][0] = __builtin_amdgcn_mfma_f32_16x16x32_bf16(apin, bi0, ar[rt][0], 0,0,0);
      ai[rt][0] = __builtin_amdgcn_mfma_f32_16x16x32_bf16(apr,  bi0, ai[rt][0], 0,0,0);
      ai[rt][0] = __builtin_amdgcn_mfma_f32_16x16x32_bf16(api,  br0, ai[rt][0], 0,0,0);
      ar[rt][1] = __builtin_amdgcn_mfma_f32_16x16x32_bf16(apr,  br1, ar[rt][1], 0,0,0);
      ar[rt][1] = __builtin_amdgcn_mfma_f32_16x16x32_bf16(apin, bi1, ar[rt][1], 0,0,0);
      ai[rt][1] = __builtin_amdgcn_mfma_f32_16x16x32_bf16(apr,  bi1, ai[rt][1], 0,0,0);
      ai[rt][1] = __builtin_amdgcn_mfma_f32_16x16x32_bf16(api,  br1, ai[rt][1], 0,0,0);
    }
  }

  // ---- out = q + g; row-norm partials via 16-lane butterfly ----
  #pragma unroll
  for (int rt = 0; rt < 2; ++rt)
    #pragma unroll
    for (int j = 0; j < 4; ++j){
      qre[rt][0][j] += ar[rt][0][j];
      qim[rt][0][j] += ai[rt][0][j];
      qre[rt][1][j] += ar[rt][1][j];
      qim[rt][1][j] += ai[rt][1][j];
      float v = qre[rt][0][j]*qre[rt][0][j] + qim[rt][0][j]*qim[rt][0][j]
              + qre[rt][1][j]*qre[rt][1][j] + qim[rt][1][j]*qim[rt][1][j];
      v += __shfl_xor(v, 1);
      v += __shfl_xor(v, 2);
      v += __shfl_xor(v, 4);
      v += __shfl_xor(v, 8);
      if (lr == 0) partials[rt*16 + lq*4 + j][wv] = v;
    }
  __syncthreads();

  // ---- finalize norms (broadcast reads, all lanes active) + scale + store --
  #pragma unroll
  for (int rt = 0; rt < 2; ++rt)
    #pragma unroll
    for (int j = 0; j < 4; ++j){
      const int rl = rt*16 + lq*4 + j;
      const f32x4 p0 = *reinterpret_cast<const f32x4*>(&partials[rl][0]);
      const f32x4 p1 = *reinterpret_cast<const f32x4*>(&partials[rl][4]);
      const float nrm = ((p0[0]+p0[1]) + (p0[2]+p0[3]))
                      + ((p1[0]+p1[1]) + (p1[2]+p1[3]));
      const float sc = (T == 0) ? 1.0f : 1.0f/(sqrtf(nrm) + EPSC);
      const size_t off = (size_t)(brow + rl)*DIM + cbase + lr;
      if (STORE_COMPLEX){
        float2 v0 = {qre[rt][0][j]*sc, qim[rt][0][j]*sc};
        float2 v1 = {qre[rt][1][j]*sc, qim[rt][1][j]*sc};
        *reinterpret_cast<float2*>(&out[off*2])      = v0;
        *reinterpret_cast<float2*>(&out[(off+16)*2]) = v1;
      } else {
        out[off]    = qre[rt][0][j]*sc;
        out[off+16] = qre[rt][1][j]*sc;
      }
    }
}

// ---------------------------------------------------------------------------
// Fallback A: single-tile apply reading Pre/Pim inline (ws fits matrices only).
// ---------------------------------------------------------------------------
template<int STORE_COMPLEX>
__global__ __launch_bounds__(512, 2)
void apply_kernel(const float* __restrict__ psi_re, const float* __restrict__ psi_im,
                  const float* __restrict__ Pre,    const float* __restrict__ Pim,
                  const int* __restrict__ tsteps,   float* __restrict__ out)
{
  __shared__ alignas(16) unsigned short a_re[64][272];
  __shared__ alignas(16) unsigned short a_im[64][272];
  __shared__ float partials[64][8];
  __shared__ float scales[64];

  const int tid  = threadIdx.x;
  const int wv   = tid >> 6;
  const int lane = tid & 63;
  const int lq   = lane >> 4;
  const int lr   = lane & 15;
  const int brow = blockIdx.x << 6;
  const int cbase = wv << 5;
  const int T = tsteps[0];

  bf16x8 bhr[2][8], bhi[2][8];
  #pragma unroll
  for (int ct = 0; ct < 2; ++ct){
    const int c = cbase + ct*16 + lr;
    #pragma unroll
    for (int kt = 0; kt < 8; ++kt){
      const int kb = kt*32 + lq*8;
      const float4 pr0 = *reinterpret_cast<const float4*>(&Pre[c*DIM + kb]);
      const float4 pr1 = *reinterpret_cast<const float4*>(&Pre[c*DIM + kb + 4]);
      const float4 pi0 = *reinterpret_cast<const float4*>(&Pim[c*DIM + kb]);
      const float4 pi1 = *reinterpret_cast<const float4*>(&Pim[c*DIM + kb + 4]);
      const float re8[8] = {pr0.x,pr0.y,pr0.z,pr0.w, pr1.x,pr1.y,pr1.z,pr1.w};
      const float im8[8] = {pi0.x,pi0.y,pi0.z,pi0.w, pi1.x,pi1.y,pi1.z,pi1.w};
      bf16x8 vr, vi;
      #pragma unroll
      for (int i = 0; i < 8; ++i){
        const float rv = re8[i] - ((c == kb + i) ? 1.0f : 0.0f);
        vr[i] = (short)f2bf(rv);
        vi[i] = (short)f2bf(im8[i]);
      }
      bhr[ct][kt] = vr; bhi[ct][kt] = vi;
    }
  }

  float sre[4][2][4], simg[4][2][4];
  #pragma unroll
  for (int rt = 0; rt < 4; ++rt)
    #pragma unroll
    for (int ct = 0; ct < 2; ++ct)
      #pragma unroll
      for (int j = 0; j < 4; ++j){
        const int row = brow + rt*16 + lq*4 + j;
        const int col = cbase + ct*16 + lr;
        const float xr = psi_re[row*DIM + col];
        const float xi = psi_im[row*DIM + col];
        sre [rt][ct][j] = xr;
        simg[rt][ct][j] = xi;
        a_re[rt*16 + lq*4 + j][col] = f2bf(xr);
        a_im[rt*16 + lq*4 + j][col] = f2bf(xi);
      }
  __syncthreads();

  #pragma unroll
  for (int rt = 0; rt < 4; ++rt){
    f32x4 ar0 = {0.f,0.f,0.f,0.f}, ar1 = {0.f,0.f,0.f,0.f};
    f32x4 ai0 = {0.f,0.f,0.f,0.f}, ai1 = {0.f,0.f,0.f,0.f};
    #pragma unroll
    for (int kt = 0; kt < 8; ++kt){
      const int arow = rt*16 + lr;
      const int kofs = kt*32 + lq*8;
      bf16x8 apr = *reinterpret_cast<const bf16x8*>(&a_re[arow][kofs]);
      bf16x8 api = *reinterpret_cast<const bf16x8*>(&a_im[arow][kofs]);
      i32x4 tneg = __builtin_bit_cast(i32x4, api) ^ (i32x4)(int)0x80008000;
      bf16x8 apin = __builtin_bit_cast(bf16x8, tneg);
      ar0 = __builtin_amdgcn_mfma_f32_16x16x32_bf16(apr,  bhr[0][kt], ar0, 0,0,0);
      ai0 = __builtin_amdgcn_mfma_f32_16x16x32_bf16(apr,  bhi[0][kt], ai0, 0,0,0);
      ar1 = __builtin_amdgcn_mfma_f32_16x16x32_bf16(apr,  bhr[1][kt], ar1, 0,0,0);
      ai1 = __builtin_amdgcn_mfma_f32_16x16x32_bf16(apr,  bhi[1][kt], ai1, 0,0,0);
      ar0 = __builtin_amdgcn_mfma_f32_16x16x32_bf16(apin, bhi[0][kt], ar0, 0,0,0);
      ai0 = __builtin_amdgcn_mfma_f32_16x16x32_bf16(api,  bhr[0][kt], ai0, 0,0,0);
      ar1 = __builtin_amdgcn_mfma_f32_16x16x32_bf16(apin, bhi[1][kt], ar1, 0,0,0);
      ai1 = __builtin_amdgcn_mfma_f32_16x16x32_bf16(api,  bhr[1][kt], ai1, 0,0,0);
    }
    float ss[4];
    #pragma unroll
    for (int j = 0; j < 4; ++j){
      sre [rt][0][j] += ar0[j];
      simg[rt][0][j] += ai0[j];
      sre [rt][1][j] += ar1[j];
      simg[rt][1][j] += ai1[j];
      float v = sre[rt][0][j]*sre[rt][0][j] + simg[rt][0][j]*simg[rt][0][j]
              + sre[rt][1][j]*sre[rt][1][j] + simg[rt][1][j]*simg[rt][1][j];
      v += __shfl_xor(v, 1);
      v += __shfl_xor(v, 2);
      v += __shfl_xor(v, 4);
      v += __shfl_xor(v, 8);
      ss[j] = v;
    }
    if (lr == 0){
      #pragma unroll
      for (int j = 0; j < 4; ++j)
        partials[rt*16 + lq*4 + j][wv] = ss[j];
    }
  }
  __syncthreads();

  if (tid < 64){
    float acc = 0.f;
    #pragma unroll
    for (int w = 0; w < 8; ++w) acc += partials[tid][w];
    scales[tid] = (T == 0) ? 1.0f : 1.0f / (sqrtf(acc) + EPSC);
  }
  __syncthreads();

  #pragma unroll
  for (int rt = 0; rt < 4; ++rt)
    #pragma unroll
    for (int ct = 0; ct < 2; ++ct)
      #pragma unroll
      for (int j = 0; j < 4; ++j){
        const int row = brow + rt*16 + lq*4 + j;
        const int col = cbase + ct*16 + lr;
        const float sc = scales[rt*16 + lq*4 + j];
        const float xr = sre [rt][ct][j] * sc;
        const float xi = simg[rt][ct][j] * sc;
        if (STORE_COMPLEX){
          float2 v2 = {xr, xi};
          *reinterpret_cast<float2*>(&out[(size_t)(row*DIM + col)*2]) = v2;
        } else {
          out[row*DIM + col] = xr;
        }
      }
}

// ---------------------------------------------------------------------------
// Fallback B: original verified 10-step kernel (used only if ws too small).
// ---------------------------------------------------------------------------
template<int STORE_COMPLEX>
__global__ __launch_bounds__(512, 2)
void qevolve_kernel(const float* __restrict__ psi_re, const float* __restrict__ psi_im,
                    const float* __restrict__ ham_re, const float* __restrict__ ham_im,
                    const float* __restrict__ hbar,   const int* __restrict__ tsteps,
                    float* __restrict__ out)
{
  __shared__ alignas(16) unsigned short a_re[64][272];
  __shared__ alignas(16) unsigned short a_im[64][272];
  __shared__ float partials[64][8];
  __shared__ float scales[64];

  const int tid  = threadIdx.x;
  const int wv   = tid >> 6;
  const int lane = tid & 63;
  const int lq   = lane >> 4;
  const int lr   = lane & 15;
  const int brow = blockIdx.x << 6;
  const int cbase = wv << 5;
  const float cs = DTC / hbar[0];
  const int T = tsteps[0];

  bf16x8 bhr[2][8], bhi[2][8];
  #pragma unroll
  for (int ct = 0; ct < 2; ++ct){
    const int c = cbase + ct*16 + lr;
    #pragma unroll
    for (int kt = 0; kt < 8; ++kt){
      const int kb = kt*32 + lq*8;
      bf16x8 vr, vi;
      #pragma unroll
      for (int i = 0; i < 8; ++i){
        vr[i] = (short)f2bf(ham_re[c*DIM + kb + i]);
        vi[i] = (short)f2bf(ham_im[c*DIM + kb + i]);
      }
      bhr[ct][kt] = vr; bhi[ct][kt] = vi;
    }
  }

  float sre[4][2][4], simg[4][2][4];
  #pragma unroll
  for (int rt = 0; rt < 4; ++rt)
    #pragma unroll
    for (int ct = 0; ct < 2; ++ct)
      #pragma unroll
      for (int j = 0; j < 4; ++j){
        const int row = brow + rt*16 + lq*4 + j;
        const int col = cbase + ct*16 + lr;
        sre [rt][ct][j] = psi_re[row*DIM + col];
        simg[rt][ct][j] = psi_im[row*DIM + col];
      }

  for (int s = 0; s < T; ++s){
    #pragma unroll
    for (int rt = 0; rt < 4; ++rt)
      #pragma unroll
      for (int ct = 0; ct < 2; ++ct)
        #pragma unroll
        for (int j = 0; j < 4; ++j){
          const int row = rt*16 + lq*4 + j;
          const int col = cbase + ct*16 + lr;
          a_re[row][col] = f2bf(sre [rt][ct][j]);
          a_im[row][col] = f2bf(simg[rt][ct][j]);
        }
    __syncthreads();

    #pragma unroll
    for (int rt = 0; rt < 4; ++rt){
      f32x4 ar0 = {0.f,0.f,0.f,0.f}, ar1 = {0.f,0.f,0.f,0.f};
      f32x4 ai0 = {0.f,0.f,0.f,0.f}, ai1 = {0.f,0.f,0.f,0.f};
      #pragma unroll
      for (int kt = 0; kt < 8; ++kt){
        const int arow = rt*16 + lr;
        const int kofs = kt*32 + lq*8;
        bf16x8 apr = *reinterpret_cast<const bf16x8*>(&a_re[arow][kofs]);
        bf16x8 api = *reinterpret_cast<const bf16x8*>(&a_im[arow][kofs]);
        i32x4 tneg = __builtin_bit_cast(i32x4, api) ^ (i32x4)(int)0x80008000;
        bf16x8 apin = __builtin_bit_cast(bf16x8, tneg);
        ar0 = __builtin_amdgcn_mfma_f32_16x16x32_bf16(apr,  bhr[0][kt], ar0, 0,0,0);
        ai0 = __builtin_amdgcn_mfma_f32_16x16x32_bf16(apr,  bhi[0][kt], ai0, 0,0,0);
        ar1 = __builtin_amdgcn_mfma_f32_16x16x32_bf16(apr,  bhr[1][kt], ar1, 0,0,0);
        ai1 = __builtin_amdgcn_mfma_f32_16x16x32_bf16(apr,  bhi[1][kt], ai1, 0,0,0);
        ar0 = __builtin_amdgcn_mfma_f32_16x16x32_bf16(apin, bhi[0][kt], ar0, 0,0,0);
        ai0 = __builtin_amdgcn_mfma_f32_16x16x32_bf16(api,  bhr[0][kt], ai0, 0,0,0);
        ar1 = __builtin_amdgcn_mfma_f32_16x16x32_bf16(apin, bhi[1][kt], ar1, 0,0,0);
        ai1 = __builtin_amdgcn_mfma_f32_16x16x32_bf16(api,  bhr[1][kt], ai1, 0,0,0);
      }
      float ss[4];
      #pragma unroll
      for (int j = 0; j < 4; ++j){
        sre [rt][0][j] += cs * ai0[j];
        simg[rt][0][j] -= cs * ar0[j];
        sre [rt][1][j] += cs * ai1[j];
        simg[rt][1][j] -= cs * ar1[j];
        float v = sre[rt][0][j]*sre[rt][0][j] + simg[rt][0][j]*simg[rt][0][j]
                + sre[rt][1][j]*sre[rt][1][j] + simg[rt][1][j]*simg[rt][1][j];
        v += __shfl_xor(v, 1);
        v += __shfl_xor(v, 2);
        v += __shfl_xor(v, 4);
        v += __shfl_xor(v, 8);
        ss[j] = v;
      }
      if (lr == 0){
        #pragma unroll
        for (int j = 0; j < 4; ++j)
          partials[rt*16 + lq*4 + j][wv] = ss[j];
      }
    }
    __syncthreads();

    if (tid < 64){
      float acc = 0.f;
      #pragma unroll
      for (int w = 0; w < 8; ++w) acc += partials[tid][w];
      scales[tid] = 1.0f / (sqrtf(acc) + EPSC);
    }
    __syncthreads();

    #pragma unroll
    for (int rt = 0; rt < 4; ++rt)
      #pragma unroll
      for (int j = 0; j < 4; ++j){
        const float sc = scales[rt*16 + lq*4 + j];
        sre [rt][0][j] *= sc; sre [rt][1][j] *= sc;
        simg[rt][0][j] *= sc; simg[rt][1][j] *= sc;
      }
  }

  #pragma unroll
  for (int rt = 0; rt < 4; ++rt)
    #pragma unroll
    for (int ct = 0; ct < 2; ++ct)
      #pragma unroll
      for (int j = 0; j < 4; ++j){
        const int row = brow + rt*16 + lq*4 + j;
        const int col = cbase + ct*16 + lr;
        if (STORE_COMPLEX){
          out[(size_t)(row*DIM + col)*2 + 0] = sre [rt][ct][j];
          out[(size_t)(row*DIM + col)*2 + 1] = simg[rt][ct][j];
        } else {
          out[row*DIM + col] = sre[rt][ct][j];
        }
      }
}

extern "C" void kernel_launch(void* const* d_in, const int* in_sizes, int n_in,
                              void* d_out, int out_size, void* d_ws, size_t ws_size,
                              hipStream_t stream)
{
  const float* psi_re = (const float*)d_in[0];
  const float* psi_im = (const float*)d_in[1];
  const float* ham_re = (const float*)d_in[2];
  const float* ham_im = (const float*)d_in[3];
  const float* hbar   = (const float*)d_in[4];
  const int*   tstep  = (const int*)d_in[5];
  float* out = (float*)d_out;

  const size_t NMAT    = (size_t)DIM * DIM;             // 65536
  const size_t WS_MAT  = 2 * NMAT * sizeof(float);      // 512 KB (P re+im)
  const size_t WS_FRAG = 2 * 8 * 2 * 512 * 16;          // 256 KB (bf16x8 frags)

  const bool cplx = (out_size == 2 * SEQ * DIM);

  if (d_ws != nullptr && ws_size >= WS_MAT){
    float* w  = (float*)d_ws;
    float* Pr = w + 0*NMAT;
    float* Pi = w + 1*NMAT;
    const bool have_frag = (ws_size >= WS_MAT + WS_FRAG);
    unsigned short* fragbuf = have_frag ? (unsigned short*)(w + 2*NMAT) : nullptr;

    // ONE launch: P = (I + cH)^T_power via (T-1) row-vector mat-vec passes,
    // M1 computed inline from H; emits P + bf16 fragments of R = P - I.
    k_power<<<256, 1024, 0, stream>>>(ham_re, ham_im, hbar, tstep, Pr, Pi, fragbuf);

    if (have_frag){
      dim3 grid(SEQ / 32), block(512);     // 4096 blocks, 2 co-resident/CU
      if (cplx)
        apply6<1><<<grid, block, 0, stream>>>(psi_re, psi_im, fragbuf, tstep, out);
      else
        apply6<0><<<grid, block, 0, stream>>>(psi_re, psi_im, fragbuf, tstep, out);
    } else {
      dim3 grid(SEQ / 64), block(512);
      if (cplx)
        apply_kernel<1><<<grid, block, 0, stream>>>(psi_re, psi_im, Pr, Pi, tstep, out);
      else
        apply_kernel<0><<<grid, block, 0, stream>>>(psi_re, psi_im, Pr, Pi, tstep, out);
    }
  } else {
    dim3 grid(SEQ / 64), block(512);
    if (cplx)
      qevolve_kernel<1><<<grid, block, 0, stream>>>(psi_re, psi_im, ham_re, ham_im, hbar, tstep, out);
    else
      qevolve_kernel<0><<<grid, block, 0, stream>>>(psi_re, psi_im, ham_re, ham_im, hbar, tstep, out);
  }

  (void)in_sizes; (void)n_in;
}

// Round 9
// 209.372 us; speedup vs baseline: 1.3202x; 1.3202x over previous
//
#include <hip/hip_runtime.h>

#define SEQ 131072
#define DIM 256
#define DTC 0.1f
#define EPSC 1e-8f

typedef __attribute__((ext_vector_type(8))) short bf16x8;
typedef __attribute__((ext_vector_type(4))) float f32x4;
typedef __attribute__((ext_vector_type(4))) int   i32x4;

// f32 -> bf16 round-to-nearest-even (no NaN handling needed: data is bounded)
static __device__ __forceinline__ unsigned short f2bf(float f){
  unsigned int u = __builtin_bit_cast(unsigned int, f);
  u += 0x7fffu + ((u >> 16) & 1u);
  return (unsigned short)(u >> 16);
}

// ---------------------------------------------------------------------------
// Chain L1 (fused init + bit4 + bit3): writes M1 = I + cH, and
//   out = (bit4 ? M1 : I)^2 * (bit3 ? M1 : I)
// Both matmul operands computed INLINE from H.  Trivial when bit4==0 (T=10).
//   cH = -i*s*(Hr + i*Hi) = s*Hi - i*s*Hr,  s = dt/hbar.
// ---------------------------------------------------------------------------
__global__ __launch_bounds__(1024)
void k_chain1(const float* __restrict__ hr, const float* __restrict__ hi,
              const float* __restrict__ hbar, const int* __restrict__ ts,
              float* __restrict__ m1r, float* __restrict__ m1i,
              float* __restrict__ outr, float* __restrict__ outi)
{
  __shared__ float rowr[256], rowi[256];
  __shared__ float pr_[4][256], pi_[4][256];
  const int tid = threadIdx.x, c = tid & 255, q = tid >> 8;
  const int r = blockIdx.x;
  const float s = DTC / hbar[0];
  const int T = ts[0];
  const bool b4 = ((T >> 4) & 1) != 0;
  const bool b3 = ((T >> 3) & 1) != 0;

  float m1rc = 0.f, m1ic = 0.f;
  if (q == 0){
    const int idx = r*256 + c;
    const float diag = (r == c) ? 1.0f : 0.0f;
    m1rc = diag + s * hi[idx];
    m1ic =       -s * hr[idx];
    m1r[idx] = m1rc;  m1i[idx] = m1ic;
  }

  if (!b4){            // block-uniform: X0 = I -> out = b3 ? M1 : I
    if (q == 0){
      const float diag = (r == c) ? 1.0f : 0.0f;
      outr[r*256+c] = b3 ? m1rc : diag;
      outi[r*256+c] = b3 ? m1ic : 0.0f;
    }
    return;
  }

  // b4 set: out = M1^2 * (b3 ? M1 : I); M1 columns computed inline from H.
  if (q == 0){ rowr[c] = m1rc; rowi[c] = m1ic; }
  __syncthreads();
  float ar = 0.f, ai = 0.f;
  const int k0 = q * 64;
  #pragma unroll 4
  for (int k = k0; k < k0 + 64; ++k){
    const int idx = k*256 + c;
    const float diag = (k == c) ? 1.0f : 0.0f;
    const float br = diag + s * hi[idx];
    const float bi =       -s * hr[idx];
    const float xr = rowr[k], xi = rowi[k];
    ar = fmaf(xr, br, fmaf(-xi, bi, ar));
    ai = fmaf(xr, bi, fmaf( xi, br, ai));
  }
  pr_[q][c] = ar; pi_[q][c] = ai;
  __syncthreads();

  if (!b3){
    if (q == 0){
      outr[r*256+c] = pr_[0][c]+pr_[1][c]+pr_[2][c]+pr_[3][c];
      outi[r*256+c] = pi_[0][c]+pi_[1][c]+pi_[2][c]+pi_[3][c];
    }
    return;
  }
  if (q == 0){
    rowr[c] = pr_[0][c]+pr_[1][c]+pr_[2][c]+pr_[3][c];
    rowi[c] = pi_[0][c]+pi_[1][c]+pi_[2][c]+pi_[3][c];
  }
  __syncthreads();
  ar = 0.f; ai = 0.f;
  #pragma unroll 4
  for (int k = k0; k < k0 + 64; ++k){
    const int idx = k*256 + c;
    const float diag = (k == c) ? 1.0f : 0.0f;
    const float br = diag + s * hi[idx];
    const float bi =       -s * hr[idx];
    const float xr = rowr[k], xi = rowi[k];
    ar = fmaf(xr, br, fmaf(-xi, bi, ar));
    ai = fmaf(xr, bi, fmaf( xi, br, ai));
  }
  pr_[q][c] = ar; pi_[q][c] = ai;
  __syncthreads();
  if (q == 0){
    outr[r*256+c] = pr_[0][c]+pr_[1][c]+pr_[2][c]+pr_[3][c];
    outi[r*256+c] = pi_[0][c]+pi_[1][c]+pi_[2][c]+pi_[3][c];
  }
}

// ---------------------------------------------------------------------------
// Square-and-multiply stage, 4-way k-split (1024 thr): out = in^2 * (bit?M1:I)
// ---------------------------------------------------------------------------
template<int BIT>
__global__ __launch_bounds__(1024)
void k_step2(const float* __restrict__ inr, const float* __restrict__ ini,
             const float* __restrict__ m1r, const float* __restrict__ m1i,
             const int* __restrict__ ts,
             float* __restrict__ outr, float* __restrict__ outi)
{
  __shared__ float rr[256], ri[256];
  __shared__ float pr_[4][256], pi_[4][256];
  const int tid = threadIdx.x, c = tid & 255, q = tid >> 8;
  const int r = blockIdx.x;
  if (q == 0){ rr[c] = inr[r*256 + c]; ri[c] = ini[r*256 + c]; }
  __syncthreads();

  float ar = 0.f, ai = 0.f;
  const int k0 = q * 64;
  #pragma unroll 8
  for (int k = k0; k < k0 + 64; ++k){
    const float br = inr[k*256 + c], bi = ini[k*256 + c];
    const float xr = rr[k],          xi = ri[k];
    ar = fmaf(xr, br, fmaf(-xi, bi, ar));
    ai = fmaf(xr, bi, fmaf( xi, br, ai));
  }
  pr_[q][c] = ar; pi_[q][c] = ai;
  __syncthreads();

  const bool bit = ((ts[0] >> BIT) & 1) != 0;
  if (!bit){
    if (q == 0){
      outr[r*256+c] = pr_[0][c]+pr_[1][c]+pr_[2][c]+pr_[3][c];
      outi[r*256+c] = pi_[0][c]+pi_[1][c]+pi_[2][c]+pi_[3][c];
    }
    return;
  }
  if (q == 0){
    rr[c] = pr_[0][c]+pr_[1][c]+pr_[2][c]+pr_[3][c];
    ri[c] = pi_[0][c]+pi_[1][c]+pi_[2][c]+pi_[3][c];
  }
  __syncthreads();
  ar = 0.f; ai = 0.f;
  #pragma unroll 8
  for (int k = k0; k < k0 + 64; ++k){
    const float br = m1r[k*256 + c], bi = m1i[k*256 + c];
    const float xr = rr[k],          xi = ri[k];
    ar = fmaf(xr, br, fmaf(-xi, bi, ar));
    ai = fmaf(xr, bi, fmaf( xi, br, ai));
  }
  pr_[q][c] = ar; pi_[q][c] = ai;
  __syncthreads();
  if (q == 0){
    outr[r*256+c] = pr_[0][c]+pr_[1][c]+pr_[2][c]+pr_[3][c];
    outi[r*256+c] = pi_[0][c]+pi_[1][c]+pi_[2][c]+pi_[3][c];
  }
}

// ---------------------------------------------------------------------------
// Chain last stage (fused bit0 + frag emission).
//   element P[r][c] -> R[C=r][K=c]:
//   ftid = (C>>5)*64 + ((K>>3)&3)*16 + (C&15);  fid = (((C>>4)&1)*8 + (K>>5))*2
// ---------------------------------------------------------------------------
__global__ __launch_bounds__(1024)
void k_last2(const float* __restrict__ inr, const float* __restrict__ ini,
             const float* __restrict__ m1r, const float* __restrict__ m1i,
             const int* __restrict__ ts,
             float* __restrict__ outr, float* __restrict__ outi,
             unsigned short* __restrict__ fragbuf)
{
  __shared__ float rr[256], ri[256];
  __shared__ float pr_[4][256], pi_[4][256];
  const int tid = threadIdx.x, c = tid & 255, q = tid >> 8;
  const int r = blockIdx.x;
  if (q == 0){ rr[c] = inr[r*256 + c]; ri[c] = ini[r*256 + c]; }
  __syncthreads();

  float ar = 0.f, ai = 0.f;
  const int k0 = q * 64;
  #pragma unroll 8
  for (int k = k0; k < k0 + 64; ++k){
    const float br = inr[k*256 + c], bi = ini[k*256 + c];
    const float xr = rr[k],          xi = ri[k];
    ar = fmaf(xr, br, fmaf(-xi, bi, ar));
    ai = fmaf(xr, bi, fmaf( xi, br, ai));
  }
  pr_[q][c] = ar; pi_[q][c] = ai;
  __syncthreads();

  const bool bit = (ts[0] & 1) != 0;
  if (bit){
    if (q == 0){
      rr[c] = pr_[0][c]+pr_[1][c]+pr_[2][c]+pr_[3][c];
      ri[c] = pi_[0][c]+pi_[1][c]+pi_[2][c]+pi_[3][c];
    }
    __syncthreads();
    ar = 0.f; ai = 0.f;
    #pragma unroll 8
    for (int k = k0; k < k0 + 64; ++k){
      const float br = m1r[k*256 + c], bi = m1i[k*256 + c];
      const float xr = rr[k],          xi = ri[k];
      ar = fmaf(xr, br, fmaf(-xi, bi, ar));
      ai = fmaf(xr, bi, fmaf( xi, br, ai));
    }
    pr_[q][c] = ar; pi_[q][c] = ai;
    __syncthreads();
  }

  if (q == 0){
    const float orr = pr_[0][c]+pr_[1][c]+pr_[2][c]+pr_[3][c];
    const float oii = pi_[0][c]+pi_[1][c]+pi_[2][c]+pi_[3][c];
    outr[r*256+c] = orr;
    outi[r*256+c] = oii;
    if (fragbuf){
      const int C = r, K = c;
      const int ftid = (C>>5)*64 + ((K>>3)&3)*16 + (C&15);
      const int fid  = (((C>>4)&1)*8 + (K>>5))*2;
      fragbuf[((size_t)fid*512     + ftid)*8 + (K&7)] = f2bf(orr - ((r==c)?1.0f:0.0f));
      fragbuf[((size_t)(fid+1)*512 + ftid)*8 + (K&7)] = f2bf(oii);
    }
  }
}

// ---------------------------------------------------------------------------
// Main apply v7: 32-row blocks (grid 4096), B streamed from L2.
// Register-liveness diet to reach 3 blocks/CU (24 waves, ~85-reg budget):
//   - ct-split MFMA: 8 live accumulators (was 16)
//   - staging re then im sequentially (halved staging liveness)
//   - residual f32 loads AFTER the MFMA loop (L1/L2-hot; frees 32 VGPR)
//   - no kt=0 hoist
//   - __launch_bounds__(512, 6)
//   out = normalize_rows( q + q @ R^T ),  R = M^T_power - I (f32 residual).
// LDS pitch 272 (r7-proven).
// ---------------------------------------------------------------------------
template<int STORE_COMPLEX>
__global__ __launch_bounds__(512, 6)
void apply7(const float* __restrict__ psi_re, const float* __restrict__ psi_im,
            const unsigned short* __restrict__ fragbuf,
            const int* __restrict__ tsteps, float* __restrict__ out)
{
  __shared__ alignas(16) unsigned short a_re[32][272];
  __shared__ alignas(16) unsigned short a_im[32][272];
  __shared__ float partials[32][8];

  const int tid  = threadIdx.x;
  const int wv   = tid >> 6;
  const int lane = tid & 63;
  const int lq   = lane >> 4;   // 16-lane group
  const int lr   = lane & 15;
  const int brow = blockIdx.x << 5;   // 32 rows per block
  const int cbase = wv << 5;          // wave's 32 columns
  const int T = tsteps[0];
  const bf16x8* fb = reinterpret_cast<const bf16x8*>(fragbuf);

  // ---- staging: row srow, 16 consecutive cols; re then im (short liveness) --
  const int srow  = tid >> 4;
  const int scol0 = (tid & 15) << 4;
  {
    const float4* p4 = reinterpret_cast<const float4*>(&psi_re[(size_t)(brow + srow)*DIM + scol0]);
    const float4 v0 = p4[0], v1 = p4[1], v2 = p4[2], v3 = p4[3];
    bf16x8 p0, p1;
    p0[0]=(short)f2bf(v0.x); p0[1]=(short)f2bf(v0.y); p0[2]=(short)f2bf(v0.z); p0[3]=(short)f2bf(v0.w);
    p0[4]=(short)f2bf(v1.x); p0[5]=(short)f2bf(v1.y); p0[6]=(short)f2bf(v1.z); p0[7]=(short)f2bf(v1.w);
    p1[0]=(short)f2bf(v2.x); p1[1]=(short)f2bf(v2.y); p1[2]=(short)f2bf(v2.z); p1[3]=(short)f2bf(v2.w);
    p1[4]=(short)f2bf(v3.x); p1[5]=(short)f2bf(v3.y); p1[6]=(short)f2bf(v3.z); p1[7]=(short)f2bf(v3.w);
    *reinterpret_cast<bf16x8*>(&a_re[srow][scol0])     = p0;
    *reinterpret_cast<bf16x8*>(&a_re[srow][scol0 + 8]) = p1;
  }
  {
    const float4* p4 = reinterpret_cast<const float4*>(&psi_im[(size_t)(brow + srow)*DIM + scol0]);
    const float4 v0 = p4[0], v1 = p4[1], v2 = p4[2], v3 = p4[3];
    bf16x8 p0, p1;
    p0[0]=(short)f2bf(v0.x); p0[1]=(short)f2bf(v0.y); p0[2]=(short)f2bf(v0.z); p0[3]=(short)f2bf(v0.w);
    p0[4]=(short)f2bf(v1.x); p0[5]=(short)f2bf(v1.y); p0[6]=(short)f2bf(v1.z); p0[7]=(short)f2bf(v1.w);
    p1[0]=(short)f2bf(v2.x); p1[1]=(short)f2bf(v2.y); p1[2]=(short)f2bf(v2.z); p1[3]=(short)f2bf(v2.w);
    p1[4]=(short)f2bf(v3.x); p1[5]=(short)f2bf(v3.y); p1[6]=(short)f2bf(v3.z); p1[7]=(short)f2bf(v3.w);
    *reinterpret_cast<bf16x8*>(&a_im[srow][scol0])     = p0;
    *reinterpret_cast<bf16x8*>(&a_im[srow][scol0 + 8]) = p1;
  }
  __syncthreads();

  // ---- ct-split complex MFMA; B streamed from L2 (2 x 16B per kt) ----
  float gre[2][2][4], gim[2][2][4];   // [rt][ct][j]
  #pragma unroll
  for (int ct = 0; ct < 2; ++ct){
    f32x4 accr[2], acci[2];
    accr[0] = (f32x4){0.f,0.f,0.f,0.f}; accr[1] = (f32x4){0.f,0.f,0.f,0.f};
    acci[0] = (f32x4){0.f,0.f,0.f,0.f}; acci[1] = (f32x4){0.f,0.f,0.f,0.f};
    #pragma unroll
    for (int kt = 0; kt < 8; ++kt){
      const bf16x8 br = fb[((ct*8 + kt)*2 + 0)*512 + tid];   // 1 KB/wave, L2
      const bf16x8 bi = fb[((ct*8 + kt)*2 + 1)*512 + tid];
      #pragma unroll
      for (int rt = 0; rt < 2; ++rt){
        const bf16x8 apr = *reinterpret_cast<const bf16x8*>(&a_re[rt*16 + lr][kt*32 + lq*8]);
        const bf16x8 api = *reinterpret_cast<const bf16x8*>(&a_im[rt*16 + lr][kt*32 + lq*8]);
        const i32x4 tneg = __builtin_bit_cast(i32x4, api) ^ (i32x4)(int)0x80008000;
        const bf16x8 apin = __builtin_bit_cast(bf16x8, tneg);   // -qi (sign flip)
        // g_re = qr@Rr - qi@Ri ; g_im = qr@Ri + qi@Rr
        accr[rt] = __builtin_amdgcn_mfma_f32_16x16x32_bf16(apr,  br, accr[rt], 0,0,0);
        accr[rt] = __builtin_amdgcn_mfma_f32_16x16x32_bf16(apin, bi, accr[rt], 0,0,0);
        acci[rt] = __builtin_amdgcn_mfma_f32_16x16x32_bf16(apr,  bi, acci[rt], 0,0,0);
        acci[rt] = __builtin_amdgcn_mfma_f32_16x16x32_bf16(api,  br, acci[rt], 0,0,0);
      }
    }
    #pragma unroll
    for (int rt = 0; rt < 2; ++rt)
      #pragma unroll
      for (int j = 0; j < 4; ++j){
        gre[rt][ct][j] = accr[rt][j];
        gim[rt][ct][j] = acci[rt][j];
      }
  }

  // ---- residual f32 re-read (D-frag layout; L1/L2-hot), out = q + g ----
  #pragma unroll
  for (int rt = 0; rt < 2; ++rt)
    #pragma unroll
    for (int ct = 0; ct < 2; ++ct)
      #pragma unroll
      for (int j = 0; j < 4; ++j){
        const size_t off = (size_t)(brow + rt*16 + lq*4 + j)*DIM + cbase + ct*16 + lr;
        gre[rt][ct][j] += psi_re[off];
        gim[rt][ct][j] += psi_im[off];
      }

  // ---- row-norm partials via 16-lane butterfly ----
  #pragma unroll
  for (int rt = 0; rt < 2; ++rt)
    #pragma unroll
    for (int j = 0; j < 4; ++j){
      float v = gre[rt][0][j]*gre[rt][0][j] + gim[rt][0][j]*gim[rt][0][j]
              + gre[rt][1][j]*gre[rt][1][j] + gim[rt][1][j]*gim[rt][1][j];
      v += __shfl_xor(v, 1);
      v += __shfl_xor(v, 2);
      v += __shfl_xor(v, 4);
      v += __shfl_xor(v, 8);
      if (lr == 0) partials[rt*16 + lq*4 + j][wv] = v;
    }
  __syncthreads();

  // ---- finalize norms (broadcast reads, all lanes active) + scale + store --
  #pragma unroll
  for (int rt = 0; rt < 2; ++rt)
    #pragma unroll
    for (int j = 0; j < 4; ++j){
      const int rl = rt*16 + lq*4 + j;
      const f32x4 p0 = *reinterpret_cast<const f32x4*>(&partials[rl][0]);
      const f32x4 p1 = *reinterpret_cast<const f32x4*>(&partials[rl][4]);
      const float nrm = ((p0[0]+p0[1]) + (p0[2]+p0[3]))
                      + ((p1[0]+p1[1]) + (p1[2]+p1[3]));
      const float sc = (T == 0) ? 1.0f : 1.0f/(sqrtf(nrm) + EPSC);
      const size_t off = (size_t)(brow + rl)*DIM + cbase + lr;
      if (STORE_COMPLEX){
        float2 v0 = {gre[rt][0][j]*sc, gim[rt][0][j]*sc};
        float2 v1 = {gre[rt][1][j]*sc, gim[rt][1][j]*sc};
        *reinterpret_cast<float2*>(&out[off*2])      = v0;
        *reinterpret_cast<float2*>(&out[(off+16)*2]) = v1;
      } else {
        out[off]    = gre[rt][0][j]*sc;
        out[off+16] = gre[rt][1][j]*sc;
      }
    }
}

// ---------------------------------------------------------------------------
// Fallback A: single-tile apply reading Pre/Pim inline (ws fits matrices only).
// ---------------------------------------------------------------------------
template<int STORE_COMPLEX>
__global__ __launch_bounds__(512, 2)
void apply_kernel(const float* __restrict__ psi_re, const float* __restrict__ psi_im,
                  const float* __restrict__ Pre,    const float* __restrict__ Pim,
                  const int* __restrict__ tsteps,   float* __restrict__ out)
{
  __shared__ alignas(16) unsigned short a_re[64][272];
  __shared__ alignas(16) unsigned short a_im[64][272];
  __shared__ float partials[64][8];
  __shared__ float scales[64];

  const int tid  = threadIdx.x;
  const int wv   = tid >> 6;
  const int lane = tid & 63;
  const int lq   = lane >> 4;
  const int lr   = lane & 15;
  const int brow = blockIdx.x << 6;
  const int cbase = wv << 5;
  const int T = tsteps[0];

  bf16x8 bhr[2][8], bhi[2][8];
  #pragma unroll
  for (int ct = 0; ct < 2; ++ct){
    const int c = cbase + ct*16 + lr;
    #pragma unroll
    for (int kt = 0; kt < 8; ++kt){
      const int kb = kt*32 + lq*8;
      const float4 pr0 = *reinterpret_cast<const float4*>(&Pre[c*DIM + kb]);
      const float4 pr1 = *reinterpret_cast<const float4*>(&Pre[c*DIM + kb + 4]);
      const float4 pi0 = *reinterpret_cast<const float4*>(&Pim[c*DIM + kb]);
      const float4 pi1 = *reinterpret_cast<const float4*>(&Pim[c*DIM + kb + 4]);
      const float re8[8] = {pr0.x,pr0.y,pr0.z,pr0.w, pr1.x,pr1.y,pr1.z,pr1.w};
      const float im8[8] = {pi0.x,pi0.y,pi0.z,pi0.w, pi1.x,pi1.y,pi1.z,pi1.w};
      bf16x8 vr, vi;
      #pragma unroll
      for (int i = 0; i < 8; ++i){
        const float rv = re8[i] - ((c == kb + i) ? 1.0f : 0.0f);
        vr[i] = (short)f2bf(rv);
        vi[i] = (short)f2bf(im8[i]);
      }
      bhr[ct][kt] = vr; bhi[ct][kt] = vi;
    }
  }

  float sre[4][2][4], simg[4][2][4];
  #pragma unroll
  for (int rt = 0; rt < 4; ++rt)
    #pragma unroll
    for (int ct = 0; ct < 2; ++ct)
      #pragma unroll
      for (int j = 0; j < 4; ++j){
        const int row = brow + rt*16 + lq*4 + j;
        const int col = cbase + ct*16 + lr;
        const float xr = psi_re[row*DIM + col];
        const float xi = psi_im[row*DIM + col];
        sre [rt][ct][j] = xr;
        simg[rt][ct][j] = xi;
        a_re[rt*16 + lq*4 + j][col] = f2bf(xr);
        a_im[rt*16 + lq*4 + j][col] = f2bf(xi);
      }
  __syncthreads();

  #pragma unroll
  for (int rt = 0; rt < 4; ++rt){
    f32x4 ar0 = {0.f,0.f,0.f,0.f}, ar1 = {0.f,0.f,0.f,0.f};
    f32x4 ai0 = {0.f,0.f,0.f,0.f}, ai1 = {0.f,0.f,0.f,0.f};
    #pragma unroll
    for (int kt = 0; kt < 8; ++kt){
      const int arow = rt*16 + lr;
      const int kofs = kt*32 + lq*8;
      bf16x8 apr = *reinterpret_cast<const bf16x8*>(&a_re[arow][kofs]);
      bf16x8 api = *reinterpret_cast<const bf16x8*>(&a_im[arow][kofs]);
      i32x4 tneg = __builtin_bit_cast(i32x4, api) ^ (i32x4)(int)0x80008000;
      bf16x8 apin = __builtin_bit_cast(bf16x8, tneg);
      ar0 = __builtin_amdgcn_mfma_f32_16x16x32_bf16(apr,  bhr[0][kt], ar0, 0,0,0);
      ai0 = __builtin_amdgcn_mfma_f32_16x16x32_bf16(apr,  bhi[0][kt], ai0, 0,0,0);
      ar1 = __builtin_amdgcn_mfma_f32_16x16x32_bf16(apr,  bhr[1][kt], ar1, 0,0,0);
      ai1 = __builtin_amdgcn_mfma_f32_16x16x32_bf16(apr,  bhi[1][kt], ai1, 0,0,0);
      ar0 = __builtin_amdgcn_mfma_f32_16x16x32_bf16(apin, bhi[0][kt], ar0, 0,0,0);
      ai0 = __builtin_amdgcn_mfma_f32_16x16x32_bf16(api,  bhr[0][kt], ai0, 0,0,0);
      ar1 = __builtin_amdgcn_mfma_f32_16x16x32_bf16(apin, bhi[1][kt], ar1, 0,0,0);
      ai1 = __builtin_amdgcn_mfma_f32_16x16x32_bf16(api,  bhr[1][kt], ai1, 0,0,0);
    }
    float ss[4];
    #pragma unroll
    for (int j = 0; j < 4; ++j){
      sre [rt][0][j] += ar0[j];
      simg[rt][0][j] += ai0[j];
      sre [rt][1][j] += ar1[j];
      simg[rt][1][j] += ai1[j];
      float v = sre[rt][0][j]*sre[rt][0][j] + simg[rt][0][j]*simg[rt][0][j]
              + sre[rt][1][j]*sre[rt][1][j] + simg[rt][1][j]*simg[rt][1][j];
      v += __shfl_xor(v, 1);
      v += __shfl_xor(v, 2);
      v += __shfl_xor(v, 4);
      v += __shfl_xor(v, 8);
      ss[j] = v;
    }
    if (lr == 0){
      #pragma unroll
      for (int j = 0; j < 4; ++j)
        partials[rt*16 + lq*4 + j][wv] = ss[j];
    }
  }
  __syncthreads();

  if (tid < 64){
    float acc = 0.f;
    #pragma unroll
    for (int w = 0; w < 8; ++w) acc += partials[tid][w];
    scales[tid] = (T == 0) ? 1.0f : 1.0f / (sqrtf(acc) + EPSC);
  }
  __syncthreads();

  #pragma unroll
  for (int rt = 0; rt < 4; ++rt)
    #pragma unroll
    for (int ct = 0; ct < 2; ++ct)
      #pragma unroll
      for (int j = 0; j < 4; ++j){
        const int row = brow + rt*16 + lq*4 + j;
        const int col = cbase + ct*16 + lr;
        const float sc = scales[rt*16 + lq*4 + j];
        const float xr = sre [rt][ct][j] * sc;
        const float xi = simg[rt][ct][j] * sc;
        if (STORE_COMPLEX){
          float2 v2 = {xr, xi};
          *reinterpret_cast<float2*>(&out[(size_t)(row*DIM + col)*2]) = v2;
        } else {
          out[row*DIM + col] = xr;
        }
      }
}

// ---------------------------------------------------------------------------
// Fallback B: original verified 10-step kernel (used only if ws too small).
// ---------------------------------------------------------------------------
template<int STORE_COMPLEX>
__global__ __launch_bounds__(512, 2)
void qevolve_kernel(const float* __restrict__ psi_re, const float* __restrict__ psi_im,
                    const float* __restrict__ ham_re, const float* __restrict__ ham_im,
                    const float* __restrict__ hbar,   const int* __restrict__ tsteps,
                    float* __restrict__ out)
{
  __shared__ alignas(16) unsigned short a_re[64][272];
  __shared__ alignas(16) unsigned short a_im[64][272];
  __shared__ float partials[64][8];
  __shared__ float scales[64];

  const int tid  = threadIdx.x;
  const int wv   = tid >> 6;
  const int lane = tid & 63;
  const int lq   = lane >> 4;
  const int lr   = lane & 15;
  const int brow = blockIdx.x << 6;
  const int cbase = wv << 5;
  const float cs = DTC / hbar[0];
  const int T = tsteps[0];

  bf16x8 bhr[2][8], bhi[2][8];
  #pragma unroll
  for (int ct = 0; ct < 2; ++ct){
    const int c = cbase + ct*16 + lr;
    #pragma unroll
    for (int kt = 0; kt < 8; ++kt){
      const int kb = kt*32 + lq*8;
      bf16x8 vr, vi;
      #pragma unroll
      for (int i = 0; i < 8; ++i){
        vr[i] = (short)f2bf(ham_re[c*DIM + kb + i]);
        vi[i] = (short)f2bf(ham_im[c*DIM + kb + i]);
      }
      bhr[ct][kt] = vr; bhi[ct][kt] = vi;
    }
  }

  float sre[4][2][4], simg[4][2][4];
  #pragma unroll
  for (int rt = 0; rt < 4; ++rt)
    #pragma unroll
    for (int ct = 0; ct < 2; ++ct)
      #pragma unroll
      for (int j = 0; j < 4; ++j){
        const int row = brow + rt*16 + lq*4 + j;
        const int col = cbase + ct*16 + lr;
        sre [rt][ct][j] = psi_re[row*DIM + col];
        simg[rt][ct][j] = psi_im[row*DIM + col];
      }

  for (int s = 0; s < T; ++s){
    #pragma unroll
    for (int rt = 0; rt < 4; ++rt)
      #pragma unroll
      for (int ct = 0; ct < 2; ++ct)
        #pragma unroll
        for (int j = 0; j < 4; ++j){
          const int row = rt*16 + lq*4 + j;
          const int col = cbase + ct*16 + lr;
          a_re[row][col] = f2bf(sre [rt][ct][j]);
          a_im[row][col] = f2bf(simg[rt][ct][j]);
        }
    __syncthreads();

    #pragma unroll
    for (int rt = 0; rt < 4; ++rt){
      f32x4 ar0 = {0.f,0.f,0.f,0.f}, ar1 = {0.f,0.f,0.f,0.f};
      f32x4 ai0 = {0.f,0.f,0.f,0.f}, ai1 = {0.f,0.f,0.f,0.f};
      #pragma unroll
      for (int kt = 0; kt < 8; ++kt){
        const int arow = rt*16 + lr;
        const int kofs = kt*32 + lq*8;
        bf16x8 apr = *reinterpret_cast<const bf16x8*>(&a_re[arow][kofs]);
        bf16x8 api = *reinterpret_cast<const bf16x8*>(&a_im[arow][kofs]);
        i32x4 tneg = __builtin_bit_cast(i32x4, api) ^ (i32x4)(int)0x80008000;
        bf16x8 apin = __builtin_bit_cast(bf16x8, tneg);
        ar0 = __builtin_amdgcn_mfma_f32_16x16x32_bf16(apr,  bhr[0][kt], ar0, 0,0,0);
        ai0 = __builtin_amdgcn_mfma_f32_16x16x32_bf16(apr,  bhi[0][kt], ai0, 0,0,0);
        ar1 = __builtin_amdgcn_mfma_f32_16x16x32_bf16(apr,  bhr[1][kt], ar1, 0,0,0);
        ai1 = __builtin_amdgcn_mfma_f32_16x16x32_bf16(apr,  bhi[1][kt], ai1, 0,0,0);
        ar0 = __builtin_amdgcn_mfma_f32_16x16x32_bf16(apin, bhi[0][kt], ar0, 0,0,0);
        ai0 = __builtin_amdgcn_mfma_f32_16x16x32_bf16(api,  bhr[0][kt], ai0, 0,0,0);
        ar1 = __builtin_amdgcn_mfma_f32_16x16x32_bf16(apin, bhi[1][kt], ar1, 0,0,0);
        ai1 = __builtin_amdgcn_mfma_f32_16x16x32_bf16(api,  bhr[1][kt], ai1, 0,0,0);
      }
      float ss[4];
      #pragma unroll
      for (int j = 0; j < 4; ++j){
        sre [rt][0][j] += cs * ai0[j];
        simg[rt][0][j] -= cs * ar0[j];
        sre [rt][1][j] += cs * ai1[j];
        simg[rt][1][j] -= cs * ar1[j];
        float v = sre[rt][0][j]*sre[rt][0][j] + simg[rt][0][j]*simg[rt][0][j]
                + sre[rt][1][j]*sre[rt][1][j] + simg[rt][1][j]*simg[rt][1][j];
        v += __shfl_xor(v, 1);
        v += __shfl_xor(v, 2);
        v += __shfl_xor(v, 4);
        v += __shfl_xor(v, 8);
        ss[j] = v;
      }
      if (lr == 0){
        #pragma unroll
        for (int j = 0; j < 4; ++j)
          partials[rt*16 + lq*4 + j][wv] = ss[j];
      }
    }
    __syncthreads();

    if (tid < 64){
      float acc = 0.f;
      #pragma unroll
      for (int w = 0; w < 8; ++w) acc += partials[tid][w];
      scales[tid] = 1.0f / (sqrtf(acc) + EPSC);
    }
    __syncthreads();

    #pragma unroll
    for (int rt = 0; rt < 4; ++rt)
      #pragma unroll
      for (int j = 0; j < 4; ++j){
        const float sc = scales[rt*16 + lq*4 + j];
        sre [rt][0][j] *= sc; sre [rt][1][j] *= sc;
        simg[rt][0][j] *= sc; simg[rt][1][j] *= sc;
      }
  }

  #pragma unroll
  for (int rt = 0; rt < 4; ++rt)
    #pragma unroll
    for (int ct = 0; ct < 2; ++ct)
      #pragma unroll
      for (int j = 0; j < 4; ++j){
        const int row = brow + rt*16 + lq*4 + j;
        const int col = cbase + ct*16 + lr;
        if (STORE_COMPLEX){
          out[(size_t)(row*DIM + col)*2 + 0] = sre [rt][ct][j];
          out[(size_t)(row*DIM + col)*2 + 1] = simg[rt][ct][j];
        } else {
          out[row*DIM + col] = sre[rt][ct][j];
        }
      }
}

extern "C" void kernel_launch(void* const* d_in, const int* in_sizes, int n_in,
                              void* d_out, int out_size, void* d_ws, size_t ws_size,
                              hipStream_t stream)
{
  const float* psi_re = (const float*)d_in[0];
  const float* psi_im = (const float*)d_in[1];
  const float* ham_re = (const float*)d_in[2];
  const float* ham_im = (const float*)d_in[3];
  const float* hbar   = (const float*)d_in[4];
  const int*   tstep  = (const int*)d_in[5];
  float* out = (float*)d_out;

  const size_t NMAT    = (size_t)DIM * DIM;             // 65536
  const size_t WS_MAT  = 6 * NMAT * sizeof(float);      // 1.5 MB
  const size_t WS_FRAG = 2 * 8 * 2 * 512 * 16;          // 256 KB (bf16x8 frags)

  const bool cplx = (out_size == 2 * SEQ * DIM);

  if (d_ws != nullptr && ws_size >= WS_MAT){
    float* w   = (float*)d_ws;
    float* m1r = w + 0*NMAT; float* m1i = w + 1*NMAT;
    float* Ar  = w + 2*NMAT; float* Ai  = w + 3*NMAT;
    float* Br  = w + 4*NMAT; float* Bi  = w + 5*NMAT;
    const bool have_frag = (ws_size >= WS_MAT + WS_FRAG);
    unsigned short* fragbuf = have_frag ? (unsigned short*)(w + 6*NMAT) : nullptr;

    // P = (I + cH)^T_power via square-and-multiply, 4 launches (r7-proven).
    k_chain1  <<<256, 1024, 0, stream>>>(ham_re, ham_im, hbar, tstep, m1r, m1i, Br, Bi);
    k_step2<2><<<256, 1024, 0, stream>>>(Br, Bi, m1r, m1i, tstep, Ar, Ai);
    k_step2<1><<<256, 1024, 0, stream>>>(Ar, Ai, m1r, m1i, tstep, Br, Bi);
    k_last2   <<<256, 1024, 0, stream>>>(Br, Bi, m1r, m1i, tstep, Ar, Ai, fragbuf);
    // final P in (Ar, Ai); bf16 fragments of R = P - I in fragbuf

    if (have_frag){
      dim3 grid(SEQ / 32), block(512);     // 4096 blocks, target 3/CU
      if (cplx)
        apply7<1><<<grid, block, 0, stream>>>(psi_re, psi_im, fragbuf, tstep, out);
      else
        apply7<0><<<grid, block, 0, stream>>>(psi_re, psi_im, fragbuf, tstep, out);
    } else {
      dim3 grid(SEQ / 64), block(512);
      if (cplx)
        apply_kernel<1><<<grid, block, 0, stream>>>(psi_re, psi_im, Ar, Ai, tstep, out);
      else
        apply_kernel<0><<<grid, block, 0, stream>>>(psi_re, psi_im, Ar, Ai, tstep, out);
    }
  } else {
    dim3 grid(SEQ / 64), block(512);
    if (cplx)
      qevolve_kernel<1><<<grid, block, 0, stream>>>(psi_re, psi_im, ham_re, ham_im, hbar, tstep, out);
    else
      qevolve_kernel<0><<<grid, block, 0, stream>>>(psi_re, psi_im, ham_re, ham_im, hbar, tstep, out);
  }

  (void)in_sizes; (void)n_in;
}